// Round 1
// baseline (3271.423 us; speedup 1.0000x reference)
//
#include <hip/hip_runtime.h>
#include <hip/hip_bf16.h>

typedef __attribute__((ext_vector_type(8))) short bf8_t;
typedef __attribute__((ext_vector_type(4))) float f32x4;

#define S_LEN 2048
#define BATCH 32
#define DH    256
#define NROW3 768
#define NCOL  1536

static __device__ __forceinline__ unsigned short f2bf(float f) {
  union { float f; unsigned u; } v; v.f = f;
  unsigned r = v.u + 0x7FFFu + ((v.u >> 16) & 1u);
  return (unsigned short)(r >> 16);
}
static __device__ __forceinline__ float bf2f(unsigned short u) {
  union { unsigned u; float f; } v; v.u = ((unsigned)u) << 16;
  return v.f;
}
static __device__ __forceinline__ float fast_sig(float x) {
  x = fminf(fmaxf(x, -30.f), 30.f);
  return __builtin_amdgcn_rcpf(1.f + __expf(-x));
}
static __device__ __forceinline__ float fast_tanh(float x) {
  x = fminf(fmaxf(x, -15.f), 15.f);
  float e = __expf(2.f * x);
  return (e - 1.f) * __builtin_amdgcn_rcpf(e + 1.f);
}
static __device__ __forceinline__ f32x4 MFMA(bf8_t a, bf8_t b, f32x4 c) {
  return __builtin_amdgcn_mfma_f32_16x16x32_bf16(a, b, c, 0, 0, 0);
}

// ---------------------------------------------------------------------------
// Kernel 1: gi = [X @ Wf^T + bf | X @ Wb^T + bb]  -> bf16, row-major 65536x1536
// Tile 128x128, BK=32, 256 threads (2x2 waves, 64x64 per wave).
// ---------------------------------------------------------------------------
__global__ __launch_bounds__(256) void gi_gemm(
    const float* __restrict__ X,
    const float* __restrict__ Wf, const float* __restrict__ Wb,
    const float* __restrict__ Bf, const float* __restrict__ Bb,
    unsigned short* __restrict__ gi)
{
  const int bid = blockIdx.x;
  const int nb = bid % 12, mb = bid / 12;      // consecutive blocks share m-block -> X L2 reuse
  const int m0 = mb * 128, n0 = nb * 128;
  const int tid = threadIdx.x;
  const int lane = tid & 63, wave = tid >> 6;
  const int wm = wave >> 1, wn = wave & 1;
  const int l15 = lane & 15, l4 = lane >> 4;

  __shared__ __align__(16) unsigned short As[128][40];  // +8 pad: bank-spread
  __shared__ __align__(16) unsigned short Bs[128][40];

  f32x4 acc[4][4];
#pragma unroll
  for (int a = 0; a < 4; ++a)
#pragma unroll
    for (int c = 0; c < 4; ++c) acc[a][c] = f32x4{0.f, 0.f, 0.f, 0.f};

  float bias[4];
#pragma unroll
  for (int nt = 0; nt < 4; ++nt) {
    int c = n0 + wn * 64 + nt * 16 + l15;
    bias[nt] = (c < NROW3) ? Bf[c] : Bb[c - NROW3];
  }

  for (int k0 = 0; k0 < 256; k0 += 32) {
#pragma unroll
    for (int i = 0; i < 4; ++i) {
      int idx = tid + 256 * i;          // 1024 units: 128 rows x 8 quads
      int r = idx >> 3, q = idx & 7;
      const float* pa = X + (size_t)(m0 + r) * 256 + k0 + q * 4;
      float4 va = *(const float4*)pa;
      unsigned long long pka =
          (unsigned long long)((unsigned)f2bf(va.x) | ((unsigned)f2bf(va.y) << 16)) |
          ((unsigned long long)((unsigned)f2bf(va.z) | ((unsigned)f2bf(va.w) << 16)) << 32);
      *(unsigned long long*)&As[r][q * 4] = pka;
      int cg = n0 + r;
      const float* pb = (cg < NROW3) ? (Wf + (size_t)cg * 256)
                                     : (Wb + (size_t)(cg - NROW3) * 256);
      float4 vb = *(const float4*)(pb + k0 + q * 4);
      unsigned long long pkb =
          (unsigned long long)((unsigned)f2bf(vb.x) | ((unsigned)f2bf(vb.y) << 16)) |
          ((unsigned long long)((unsigned)f2bf(vb.z) | ((unsigned)f2bf(vb.w) << 16)) << 32);
      *(unsigned long long*)&Bs[r][q * 4] = pkb;
    }
    __syncthreads();
    bf8_t af[4], bv[4];
#pragma unroll
    for (int mt = 0; mt < 4; ++mt)
      af[mt] = *(const bf8_t*)&As[wm * 64 + mt * 16 + l15][l4 * 8];
#pragma unroll
    for (int nt = 0; nt < 4; ++nt)
      bv[nt] = *(const bf8_t*)&Bs[wn * 64 + nt * 16 + l15][l4 * 8];
#pragma unroll
    for (int mt = 0; mt < 4; ++mt)
#pragma unroll
      for (int nt = 0; nt < 4; ++nt)
        acc[mt][nt] = MFMA(af[mt], bv[nt], acc[mt][nt]);
    __syncthreads();
  }
#pragma unroll
  for (int mt = 0; mt < 4; ++mt) {
#pragma unroll
    for (int nt = 0; nt < 4; ++nt) {
      int row = m0 + wm * 64 + mt * 16 + l4 * 4;
      int col = n0 + wn * 64 + nt * 16 + l15;
#pragma unroll
      for (int q = 0; q < 4; ++q)
        gi[(size_t)(row + q) * NCOL + col] = f2bf(acc[mt][nt][q] + bias[nt]);
    }
  }
}

// ---------------------------------------------------------------------------
// Kernel 2: persistent-weight GRU recurrence. One workgroup per (batch, dir).
// 512 threads = 8 waves; wave w owns W_hh rows [96w, 96w+96) as 6 MFMA A-tiles,
// kept in VGPRs for all 2048 steps. h lives in LDS (bf16) + per-thread fp32.
// ---------------------------------------------------------------------------
__global__ __launch_bounds__(512) void rnn_rec(
    const float* __restrict__ v_in,
    const float* __restrict__ Whf, const float* __restrict__ Whb,
    const float* __restrict__ bhf, const float* __restrict__ bhb,
    const unsigned short* __restrict__ gi,
    const int* __restrict__ clp,
    float* __restrict__ out)
{
  const int bid = blockIdx.x;       // 0..63
  const int dir = bid & 1;
  const int b   = bid >> 1;
  const int tid = threadIdx.x;
  const int lane = tid & 63, wave = tid >> 6;
  const int l15 = lane & 15, l4 = lane >> 4;
  const int cl = clp[0];
  const int rows_out = S_LEN - 2 * cl;

  const float* W   = dir ? Whb : Whf;
  const float* bhh = dir ? bhb : bhf;

  __shared__ __align__(16) unsigned short h_lds[DH];   // h as bf16 (MFMA B operand)
  __shared__ float gh_lds[NROW3];                      // h @ W_hh^T staging

  // --- load W_hh into persistent A-fragments (6 tiles x 8 k-chunks x 4 VGPR) ---
  bf8_t afrag[6][8];
#pragma unroll
  for (int m = 0; m < 6; ++m) {
    const int row = (wave * 6 + m) * 16 + l15;         // A: m = lane&15
    const float* wr = W + (size_t)row * 256 + l4 * 8;  // k = 8*(lane>>4)+j
#pragma unroll
    for (int c = 0; c < 8; ++c) {
      const float* src = wr + c * 32;
      bf8_t f;
#pragma unroll
      for (int j = 0; j < 8; ++j) f[j] = (short)f2bf(src[j]);
      afrag[m][c] = f;
    }
  }

  if (tid < DH) h_lds[tid] = 0;
  float h_reg = 0.f;
  float bh_r = 0.f, bh_z = 0.f, bh_n = 0.f;
  const size_t vbase = (size_t)b * S_LEN * DH;
  const unsigned short* gib = gi + (size_t)b * S_LEN * NCOL + dir * NROW3;

  // prefetch step 0 gi / v
  unsigned short p_r = 0, p_z = 0, p_n = 0;
  float p_v = 0.f;
  if (tid < DH) {
    bh_r = bhh[tid]; bh_z = bhh[DH + tid]; bh_n = bhh[2 * DH + tid];
    const int t0 = dir ? (S_LEN - 1) : 0;
    const unsigned short* g = gib + (size_t)t0 * NCOL;
    p_r = g[tid]; p_z = g[DH + tid]; p_n = g[2 * DH + tid];
    p_v = v_in[vbase + (size_t)t0 * DH + tid];
  }
  __syncthreads();

#pragma unroll 1
  for (int s = 0; s < S_LEN; ++s) {
    const float gir = bf2f(p_r), giz = bf2f(p_z), gin = bf2f(p_n), vv = p_v;
    // prefetch next step (full-step slack hides HBM latency)
    if (tid < DH && s + 1 < S_LEN) {
      const int tn = dir ? (S_LEN - 2 - s) : (s + 1);
      const unsigned short* g = gib + (size_t)tn * NCOL;
      p_r = g[tid]; p_z = g[DH + tid]; p_n = g[2 * DH + tid];
      p_v = v_in[vbase + (size_t)tn * DH + tid];
    }

    // gh = h @ W_hh^T : 48 MFMAs/wave, B = h broadcast across columns
    f32x4 acc[6];
#pragma unroll
    for (int m = 0; m < 6; ++m) acc[m] = f32x4{0.f, 0.f, 0.f, 0.f};
#pragma unroll
    for (int c = 0; c < 8; ++c) {
      bf8_t bv = *(const bf8_t*)&h_lds[c * 32 + l4 * 8];  // broadcast in 16-lane groups
#pragma unroll
      for (int m = 0; m < 6; ++m) acc[m] = MFMA(afrag[m][c], bv, acc[m]);
    }
    // extract column 0 of each C tile (all columns identical)
    if (l15 == 0) {
#pragma unroll
      for (int m = 0; m < 6; ++m) {
        const int rb = (wave * 6 + m) * 16 + l4 * 4;  // C: row = 4*(lane>>4)+q
        gh_lds[rb + 0] = acc[m][0];
        gh_lds[rb + 1] = acc[m][1];
        gh_lds[rb + 2] = acc[m][2];
        gh_lds[rb + 3] = acc[m][3];
      }
    }
    __syncthreads();
    // gates on threads 0..255 (waves 0-3); h kept fp32 in h_reg
    if (tid < DH) {
      const float r = fast_sig(gh_lds[tid] + bh_r + gir);
      const float z = fast_sig(gh_lds[DH + tid] + bh_z + giz);
      const float n = fast_tanh(gin + r * (gh_lds[2 * DH + tid] + bh_n));
      const float h2 = (1.f - z) * n + z * h_reg;
      h_reg = h2;
      h_lds[tid] = f2bf(h2);
      if (s >= cl && s < S_LEN - cl) {
        out[((size_t)b * rows_out + (s - cl)) * (2 * DH) + dir * DH + tid] = h2 + vv;
      }
    }
    __syncthreads();
  }
}

// ---------------------------------------------------------------------------
extern "C" void kernel_launch(void* const* d_in, const int* in_sizes, int n_in,
                              void* d_out, int out_size, void* d_ws, size_t ws_size,
                              hipStream_t stream) {
  const float* v_in   = (const float*)d_in[0];
  const float* w_ih_f = (const float*)d_in[1];
  const float* w_hh_f = (const float*)d_in[2];
  const float* b_ih_f = (const float*)d_in[3];
  const float* b_hh_f = (const float*)d_in[4];
  const float* w_ih_b = (const float*)d_in[5];
  const float* w_hh_b = (const float*)d_in[6];
  const float* b_ih_b = (const float*)d_in[7];
  const float* b_hh_b = (const float*)d_in[8];
  const int*   clp    = (const int*)d_in[9];
  float* out = (float*)d_out;
  unsigned short* gi = (unsigned short*)d_ws;   // 65536 x 1536 bf16 = 201 MB

  gi_gemm<<<dim3(512 * 12), dim3(256), 0, stream>>>(
      v_in, w_ih_f, w_ih_b, b_ih_f, b_ih_b, gi);
  rnn_rec<<<dim3(64), dim3(512), 0, stream>>>(
      v_in, w_hh_f, w_hh_b, b_hh_f, b_hh_b, gi, clp, out);
}